// Round 6
// baseline (309.767 us; speedup 1.0000x reference)
//
#include <hip/hip_runtime.h>
#include <hip/hip_bf16.h>

#define GENES 20000
#define NB    4096
#define GOUT  20000
#define GPAD  20096   // GOUT padded to multiple of 128

typedef __attribute__((ext_vector_type(8))) short bf16x8;
typedef __attribute__((ext_vector_type(4))) float f32x4;

__device__ __forceinline__ unsigned short f2bf(float f) {
    unsigned int u = __float_as_uint(f);
    unsigned int lsb = (u >> 16) & 1u;
    u += 0x7fffu + lsb;                      // RTNE
    return (unsigned short)(u >> 16);
}
__device__ __forceinline__ unsigned int f2bf2(float a, float b) {
    return (unsigned int)f2bf(a) | ((unsigned int)f2bf(b) << 16);
}

// LDS fence: all prior DS ops complete, nothing crosses (rule #18 ordering)
#define LDS_FENCE() do { \
    asm volatile("s_waitcnt lgkmcnt(0)" ::: "memory"); \
    __builtin_amdgcn_sched_barrier(0); \
} while (0)

// ---------------- K0a: W1,W2 -> plain transposed bf16 (row-major [h][d]) -----
__global__ void prep_weights(const float* __restrict__ W1, const float* __restrict__ W2,
                             unsigned short* __restrict__ w1t, unsigned short* __restrict__ w2t) {
    int o = blockIdx.x * 512 + threadIdx.x;
#pragma unroll
    for (int k = 0; k < 2; ++k, o += 256) {
        int h = o >> 7, d = o & 127;
        w1t[o] = f2bf(W1[d * 128 + h]);   // W1T[h][d] = W1[d][h]
        w2t[o] = f2bf(W2[d * 128 + h]);
    }
}

// ---------------- K0b: Wout [128][20000] f32 -> WoutT [20096][128] bf16 -------
__global__ void prep_wout(const float* __restrict__ Wout, unsigned short* __restrict__ woutT) {
    int g = blockIdx.x * 256 + threadIdx.x;
    if (g >= GPAD) return;
    if (g < GOUT) {
        for (int d0 = 0; d0 < 128; d0 += 8) {
            unsigned short buf[8];
#pragma unroll
            for (int j = 0; j < 8; ++j) buf[j] = f2bf(Wout[(size_t)(d0 + j) * GOUT + g]);
            *reinterpret_cast<uint4*>(&woutT[(size_t)g * 128 + d0]) =
                *reinterpret_cast<const uint4*>(buf);
        }
    } else {
        uint4 z = {0u, 0u, 0u, 0u};
        for (int d0 = 0; d0 < 128; d0 += 8)
            *reinterpret_cast<uint4*>(&woutT[(size_t)g * 128 + d0]) = z;
    }
}

// ---------------- K1: 1 wave = 1 combo, zero block barriers -------------------
// LDS bounce is double-buffered by colt parity AND fenced (lgkmcnt(0) +
// sched_barrier) at both RAW and WAR edges — fixes R5's replay divergence.
__global__ __launch_bounds__(256, 2) void encoder_kernel(
    const float* __restrict__ gene, const float* __restrict__ b1g,
    const float* __restrict__ b2g, const float* __restrict__ pwg,
    const int* __restrict__ locs_gene, const int* __restrict__ locs_combos,
    const unsigned short* __restrict__ w1t, const unsigned short* __restrict__ w2t,
    unsigned short* __restrict__ poolbf)
{
    __shared__ __align__(16) unsigned short h1lds[4][2][16 * 136];  // 34.8 KB

    const int t = threadIdx.x;
    const int lane = t & 63, wv = t >> 6;
    const int r = lane & 15, kg = lane >> 4;
    const int c = blockIdx.x * 4 + wv;                 // combo id
    const int g0 = locs_gene[2 * c], g1 = locs_gene[2 * c + 1];

    // ---- pass A: load X B-frags (4 col-tiles), colsum enroute ----
    bf16x8 b1f[4][4];
    float csv[4];
#pragma unroll
    for (int colt = 0; colt < 4; ++colt) {
        const int gs = (colt >> 1) ? g1 : g0;
        const float* base = gene + (size_t)gs * 4096 + kg * 256 + (colt & 1) * 16 + r;
        float f[4][8];
#pragma unroll
        for (int ks = 0; ks < 4; ++ks)
#pragma unroll
            for (int j = 0; j < 8; ++j)
                f[ks][j] = base[ks * 1024 + j * 32];   // d = ks*32 + kg*8 + j
        float cs = 0.f;
#pragma unroll
        for (int ks = 0; ks < 4; ++ks)
#pragma unroll
            for (int j = 0; j < 8; ++j) cs += f[ks][j];
        csv[colt] = cs;
#pragma unroll
        for (int ks = 0; ks < 4; ++ks) {
            bf16x8 v;
#pragma unroll
            for (int j = 0; j < 8; ++j) v[j] = (short)f2bf(f[ks][j]);
            b1f[colt][ks] = v;
        }
    }
    // colsum over all 128 d: reduce across the 4 kg-lane groups
#pragma unroll
    for (int colt = 0; colt < 4; ++colt) {
        csv[colt] += __shfl_xor(csv[colt], 16);
        csv[colt] += __shfl_xor(csv[colt], 32);
    }
    // ---- mask + masked softmax over 32 pathways, all in-register ----
    // cols: colt0=(g0,p=r) colt1=(g0,16+r) colt2=(g1,r) colt3=(g1,16+r)
    bool m0 = (csv[0] != 0.f) || (csv[2] != 0.f);
    bool m1 = (csv[1] != 0.f) || (csv[3] != 0.f);
    float l0 = m0 ? pwg[r] : -1e9f;
    float l1 = m1 ? pwg[16 + r] : -1e9f;
    float M = fmaxf(l0, l1);
#pragma unroll
    for (int o = 8; o >= 1; o >>= 1) M = fmaxf(M, __shfl_xor(M, o));
    float e0 = __expf(l0 - M), e1 = __expf(l1 - M);
    float se = e0 + e1;
#pragma unroll
    for (int o = 8; o >= 1; o >>= 1) se += __shfl_xor(se, o);
    const float w0 = e0 / se, w1 = e1 / se;

    // ---- pass B: MLP per col-tile, pooling with softmax weights ----
    f32x4 pool[8];
#pragma unroll
    for (int mt = 0; mt < 8; ++mt) { f32x4 z = {0.f,0.f,0.f,0.f}; pool[mt] = z; }

#pragma unroll
    for (int colt = 0; colt < 4; ++colt) {
        const float wcol = (colt & 1) ? w1 : w0;
        unsigned short* h1w = &h1lds[wv][colt & 1][0];
        // layer 1: acc[h-tile] = W1T(A) @ X(B); write H1 to wave-private LDS
#pragma unroll
        for (int mt = 0; mt < 8; ++mt) {
            f32x4 acc = {0.f, 0.f, 0.f, 0.f};
#pragma unroll
            for (int ks = 0; ks < 4; ++ks) {
                bf16x8 a1 = *reinterpret_cast<const bf16x8*>(
                    &w1t[(mt * 16 + r) * 128 + ks * 32 + kg * 8]);
                acc = __builtin_amdgcn_mfma_f32_16x16x32_bf16(a1, b1f[colt][ks], acc, 0, 0, 0);
            }
            float4 bb = *reinterpret_cast<const float4*>(&b1g[mt * 16 + kg * 4]);
            float x0 = acc[0] + bb.x; x0 = (x0 >= 0.f) ? x0 : 0.01f * x0;
            float x1 = acc[1] + bb.y; x1 = (x1 >= 0.f) ? x1 : 0.01f * x1;
            float x2 = acc[2] + bb.z; x2 = (x2 >= 0.f) ? x2 : 0.01f * x2;
            float x3 = acc[3] + bb.w; x3 = (x3 >= 0.f) ? x3 : 0.01f * x3;
            uint2 pk = {f2bf2(x0, x1), f2bf2(x2, x3)};
            *reinterpret_cast<uint2*>(&h1w[r * 136 + mt * 16 + kg * 4]) = pk;
        }
        LDS_FENCE();   // RAW: all H1 writes complete before cross-lane reads
        // repack: read H1 as layer-2 B-frags (k = h contiguous per lane)
        bf16x8 b2f[4];
#pragma unroll
        for (int ks = 0; ks < 4; ++ks)
            b2f[ks] = *reinterpret_cast<const bf16x8*>(&h1w[r * 136 + ks * 32 + kg * 8]);
        LDS_FENCE();   // WAR: reads complete before any later writes to strip
        // layer 2 + leaky + weighted pooling
#pragma unroll
        for (int mt = 0; mt < 8; ++mt) {
            f32x4 acc = {0.f, 0.f, 0.f, 0.f};
#pragma unroll
            for (int ks = 0; ks < 4; ++ks) {
                bf16x8 a2 = *reinterpret_cast<const bf16x8*>(
                    &w2t[(mt * 16 + r) * 128 + ks * 32 + kg * 8]);
                acc = __builtin_amdgcn_mfma_f32_16x16x32_bf16(a2, b2f[ks], acc, 0, 0, 0);
            }
            float4 bb = *reinterpret_cast<const float4*>(&b2g[mt * 16 + kg * 4]);
#pragma unroll
            for (int i = 0; i < 4; ++i) {
                float x = acc[i] + (&bb.x)[i];
                x = (x >= 0.f) ? x : 0.01f * x;
                pool[mt][i] = fmaf(x, wcol, pool[mt][i]);
            }
        }
        __builtin_amdgcn_sched_barrier(0);
    }
    // ---- reduce pooled over the 16 col-lanes ----
#pragma unroll
    for (int mt = 0; mt < 8; ++mt)
#pragma unroll
        for (int i = 0; i < 4; ++i) {
            float v = pool[mt][i];
            v += __shfl_xor(v, 1);
            v += __shfl_xor(v, 2);
            v += __shfl_xor(v, 4);
            v += __shfl_xor(v, 8);
            pool[mt][i] = v;
        }
    // lane (r<8, kg) stores h = r*16 + kg*4 .. +4 (static-index select chain)
    if (r < 8) {
        f32x4 v = pool[0];
#pragma unroll
        for (int k = 1; k < 8; ++k) if (r == k) v = pool[k];
        uint2 pk = {f2bf2(v[0], v[1]), f2bf2(v[2], v[3])};
        int seg = locs_combos[2 * c];
        *reinterpret_cast<uint2*>(&poolbf[(size_t)seg * 128 + r * 16 + kg * 4]) = pk;
    }
}

// ---------------- K2: out = pooled @ Wout + bout  (register-only MFMA) --------
__global__ __launch_bounds__(256) void out_gemm(
    const unsigned short* __restrict__ poolbf, const unsigned short* __restrict__ woutT,
    const float* __restrict__ boutg, float* __restrict__ out)
{
    int t = threadIdx.x;
    int lane = t & 63, wv = t >> 6;
    int nb0 = blockIdx.x * 128;
    int mb0 = blockIdx.y * 128 + wv * 32;
    int nrow = lane & 15, kg = lane >> 4;

    bf16x8 afr[2][4];
#pragma unroll
    for (int mt = 0; mt < 2; ++mt) {
        int row = mb0 + mt * 16 + nrow;
#pragma unroll
        for (int ks = 0; ks < 4; ++ks)
            afr[mt][ks] = *reinterpret_cast<const bf16x8*>(
                &poolbf[(size_t)row * 128 + ks * 32 + kg * 8]);
    }
#pragma unroll
    for (int nt = 0; nt < 8; ++nt) {
        int n = nb0 + nt * 16 + nrow;          // < 20096 always (padded)
        f32x4 a0 = {0.f, 0.f, 0.f, 0.f}, a1 = {0.f, 0.f, 0.f, 0.f};
#pragma unroll
        for (int ks = 0; ks < 4; ++ks) {
            bf16x8 bfr = *reinterpret_cast<const bf16x8*>(
                &woutT[(size_t)n * 128 + ks * 32 + kg * 8]);
            a0 = __builtin_amdgcn_mfma_f32_16x16x32_bf16(afr[0][ks], bfr, a0, 0, 0, 0);
            a1 = __builtin_amdgcn_mfma_f32_16x16x32_bf16(afr[1][ks], bfr, a1, 0, 0, 0);
        }
        int col = nb0 + nt * 16 + nrow;
        if (col < GOUT) {
            float bias = boutg[col];
#pragma unroll
            for (int i = 0; i < 4; ++i) {
                int r0 = mb0 + kg * 4 + i;
                out[(size_t)r0 * GOUT + col] = a0[i] + bias;
                out[(size_t)(r0 + 16) * GOUT + col] = a1[i] + bias;
            }
        }
    }
}

extern "C" void kernel_launch(void* const* d_in, const int* in_sizes, int n_in,
                              void* d_out, int out_size, void* d_ws, size_t ws_size,
                              hipStream_t stream) {
    const float* gene  = (const float*)d_in[0];
    const float* W1    = (const float*)d_in[1];
    const float* b1    = (const float*)d_in[2];
    const float* W2    = (const float*)d_in[3];
    const float* b2    = (const float*)d_in[4];
    const float* pw    = (const float*)d_in[5];
    const float* Wout  = (const float*)d_in[6];
    const float* bout  = (const float*)d_in[7];
    const int* locs_gene   = (const int*)d_in[8];
    const int* locs_combos = (const int*)d_in[9];
    float* out = (float*)d_out;

    char* ws = (char*)d_ws;
    unsigned short* w1t    = (unsigned short*)(ws);
    unsigned short* w2t    = (unsigned short*)(ws + 32768);
    unsigned short* woutT  = (unsigned short*)(ws + 65536);
    unsigned short* poolbf = (unsigned short*)(ws + 65536 + (size_t)GPAD * 256);

    hipLaunchKernelGGL(prep_weights, dim3(32), dim3(256), 0, stream, W1, W2, w1t, w2t);
    hipLaunchKernelGGL(prep_wout, dim3((GPAD + 255) / 256), dim3(256), 0, stream, Wout, woutT);
    hipLaunchKernelGGL(encoder_kernel, dim3(NB / 4), dim3(256), 0, stream,
                       gene, b1, b2, pw, locs_gene, locs_combos, w1t, w2t, poolbf);
    hipLaunchKernelGGL(out_gemm, dim3(GPAD / 128, 32), dim3(256), 0, stream,
                       poolbf, woutT, bout, out);
}

// Round 7
// 255.410 us; speedup vs baseline: 1.2128x; 1.2128x over previous
//
#include <hip/hip_runtime.h>
#include <hip/hip_bf16.h>

#define GENES 20000
#define DD    128
#define PP    32
#define HH    128
#define NB    4096
#define GOUT  20000
#define GPAD  20096   // GOUT padded to multiple of 128
#define CPB   16      // combos per encoder block

typedef __attribute__((ext_vector_type(8))) short bf16x8;
typedef __attribute__((ext_vector_type(4))) float f32x4;

__device__ __forceinline__ unsigned short f2bf(float f) {
    unsigned int u = __float_as_uint(f);
    unsigned int lsb = (u >> 16) & 1u;
    u += 0x7fffu + lsb;                      // RTNE
    return (unsigned short)(u >> 16);
}
__device__ __forceinline__ float bf2f(unsigned short s) {
    return __uint_as_float(((unsigned int)s) << 16);
}
__device__ __forceinline__ unsigned int f2bf2(float a, float b) {
    return (unsigned int)f2bf(a) | ((unsigned int)f2bf(b) << 16);
}

// XOR-swizzled ushort offset inside a [rows][128] bf16 tile (16B-chunk swizzle).
__device__ __forceinline__ int swz(int r, int c) {
    return r * 128 + (((c >> 3) ^ (r & 15)) << 3) + (c & 7);
}

// ---------------- K0a: W1,W2 -> swizzled bf16 transposed tiles (R2 exact) -----
__global__ void prep_weights(const float* __restrict__ W1, const float* __restrict__ W2,
                             unsigned short* __restrict__ w1t, unsigned short* __restrict__ w2t) {
    int idx = blockIdx.x * 512 + threadIdx.x;
#pragma unroll
    for (int k = 0; k < 2; ++k, idx += 256) {
        int d = idx >> 7, h = idx & 127;
        int off = swz(h, d);       // W1T[h][d] = W1[d][h]
        w1t[off] = f2bf(W1[idx]);
        w2t[off] = f2bf(W2[idx]);
    }
}

// ---------------- K0b: Wout [128][20000] f32 -> WoutT [20096][128] bf16 -------
__global__ void prep_wout(const float* __restrict__ Wout, unsigned short* __restrict__ woutT) {
    int g = blockIdx.x * 256 + threadIdx.x;
    if (g >= GPAD) return;
    if (g < GOUT) {
        for (int d0 = 0; d0 < 128; d0 += 8) {
            unsigned short buf[8];
#pragma unroll
            for (int j = 0; j < 8; ++j) buf[j] = f2bf(Wout[(size_t)(d0 + j) * GOUT + g]);
            *reinterpret_cast<uint4*>(&woutT[(size_t)g * 128 + d0]) =
                *reinterpret_cast<const uint4*>(buf);
        }
    } else {
        uint4 z = {0u, 0u, 0u, 0u};
        for (int d0 = 0; d0 < 128; d0 += 8)
            *reinterpret_cast<uint4*>(&woutT[(size_t)g * 128 + d0]) = z;
    }
}

// ---------------- K1: persistent encoder, pipelined gather (R2 exact) ---------
__global__ __launch_bounds__(512) void encoder_kernel(
    const float* __restrict__ gene, const float* __restrict__ b1g,
    const float* __restrict__ b2g, const float* __restrict__ pwg,
    const int* __restrict__ locs_gene, const int* __restrict__ locs_combos,
    const unsigned short* __restrict__ w1t, const unsigned short* __restrict__ w2t,
    unsigned short* __restrict__ poolbf)
{
    __shared__ __align__(16) unsigned short w1L[128 * 128];     // 32 KB swizzled
    __shared__ __align__(16) unsigned short w2L[128 * 128];     // 32 KB swizzled
    __shared__ __align__(16) unsigned short aBuf[2][64 * 128];  // 2 x 16 KB swizzled
    __shared__ float wrow[64];
    __shared__ float pp[8][128];

    const int t = threadIdx.x;
    const int lane = t & 63, wv = t >> 6;
    const int nrow = lane & 15, kg = lane >> 4;
    const int mt = wv >> 1, nh = wv & 1;          // wave -> (M-tile, N-half)
    const int rA = mt * 16 + nrow;

    // ---- stage weights once per block
    {
        const uint4* s1 = reinterpret_cast<const uint4*>(w1t);
        const uint4* s2 = reinterpret_cast<const uint4*>(w2t);
        uint4* d1 = reinterpret_cast<uint4*>(w1L);
        uint4* d2 = reinterpret_cast<uint4*>(w2L);
        for (int i = t; i < 2048; i += 512) { d1[i] = s1[i]; d2[i] = s2[i]; }
    }
    // ---- per-thread invariants
    float b1r[4], b2r[4];
#pragma unroll
    for (int nt = 0; nt < 4; ++nt) {
        int c = nh * 64 + nt * 16 + nrow;
        b1r[nt] = b1g[c]; b2r[nt] = b2g[c];
    }
    const float pwl = pwg[lane & 31];

    // staging decomposition: thread -> (gene slot, d-quad, p-quad)
    const int sl = t >> 8;                 // 0..1 (which gene of the combo)
    const int w8 = t & 255;
    const int d0 = (w8 >> 3) * 4;          // 0,4,...,124
    const int pq = w8 & 7;                 // p-quad 0..7

    const int c0 = blockIdx.x * CPB;

    float4 pf[4];
    // ---- prologue: load + stage combo c0 into aBuf[0]
    {
        int g0 = locs_gene[2 * c0], g1 = locs_gene[2 * c0 + 1];
        const float* src = gene + (size_t)(sl ? g1 : g0) * 4096;
#pragma unroll
        for (int i = 0; i < 4; ++i)
            pf[i] = *reinterpret_cast<const float4*>(&src[(d0 + i) * 32 + pq * 4]);
#pragma unroll
        for (int q = 0; q < 4; ++q) {
            int r = sl * 32 + pq * 4 + q;
            unsigned int lo = (unsigned int)f2bf((&pf[0].x)[q]) |
                              ((unsigned int)f2bf((&pf[1].x)[q]) << 16);
            unsigned int hi = (unsigned int)f2bf((&pf[2].x)[q]) |
                              ((unsigned int)f2bf((&pf[3].x)[q]) << 16);
            uint2 v2 = {lo, hi};
            *reinterpret_cast<uint2*>(
                &aBuf[0][r * 128 + (((d0 >> 3) ^ (r & 15)) << 3) + (d0 & 7)]) = v2;
        }
    }
    __syncthreads();

    int cur = 0;
    for (int j = 0; j < CPB; ++j) {
        const int c = c0 + j;
        // ---- issue prefetch loads for combo c+1 (latency hides under MFMA)
        if (j + 1 < CPB) {
            int g0 = locs_gene[2 * (c + 1)], g1 = locs_gene[2 * (c + 1) + 1];
            const float* src = gene + (size_t)(sl ? g1 : g0) * 4096;
#pragma unroll
            for (int i = 0; i < 4; ++i)
                pf[i] = *reinterpret_cast<const float4*>(&src[(d0 + i) * 32 + pq * 4]);
        }
        const unsigned short* A = aBuf[cur];
        unsigned short* Aw = aBuf[cur];

        // ---- wave 0: per-row colsum -> mask -> softmax -> wrow[64]
        if (wv == 0) {
            float cs = 0.f;
#pragma unroll
            for (int cch = 0; cch < 16; ++cch) {
                int phys = cch ^ (lane & 15);
                bf16x8 v = *reinterpret_cast<const bf16x8*>(&A[lane * 128 + phys * 8]);
#pragma unroll
                for (int q = 0; q < 8; ++q) cs += bf2f((unsigned short)v[q]);
            }
            float other = __shfl_down(cs, 32);
            bool m = (cs != 0.f) || (other != 0.f);
            float logit = m ? pwl : -1e9f;
            float mx = logit;
#pragma unroll
            for (int o = 16; o >= 1; o >>= 1) mx = fmaxf(mx, __shfl_xor(mx, o, 32));
            float e = __expf(logit - mx);
            float se = e;
#pragma unroll
            for (int o = 16; o >= 1; o >>= 1) se += __shfl_xor(se, o, 32);
            float w = e / se;
            if (lane < 32) { wrow[lane] = w; wrow[lane + 32] = w; }
        }

        // ---- layer 1: H1 = leaky(A @ W1 + b1)
        bf16x8 afr[4];
#pragma unroll
        for (int ks = 0; ks < 4; ++ks) {
            int phys = (ks * 4 + kg) ^ (rA & 15);
            afr[ks] = *reinterpret_cast<const bf16x8*>(&A[rA * 128 + phys * 8]);
        }
        f32x4 acc1[4];
#pragma unroll
        for (int nt = 0; nt < 4; ++nt) {
            f32x4 acc = {0.f, 0.f, 0.f, 0.f};
            int n = nh * 64 + nt * 16 + nrow;
#pragma unroll
            for (int ks = 0; ks < 4; ++ks) {
                int phys = (ks * 4 + kg) ^ (n & 15);
                bf16x8 bfr = *reinterpret_cast<const bf16x8*>(&w1L[n * 128 + phys * 8]);
                acc = __builtin_amdgcn_mfma_f32_16x16x32_bf16(afr[ks], bfr, acc, 0, 0, 0);
            }
            acc1[nt] = acc;
        }
        __syncthreads();   // (1) all aBuf[cur] reads + wrow write done

        // ---- write H1 back into aBuf[cur] (swizzled)
#pragma unroll
        for (int nt = 0; nt < 4; ++nt) {
            int cc = nh * 64 + nt * 16 + nrow;
#pragma unroll
            for (int i = 0; i < 4; ++i) {
                int r = mt * 16 + kg * 4 + i;
                float x = acc1[nt][i] + b1r[nt];
                x = (x >= 0.f) ? x : 0.01f * x;
                Aw[swz(r, cc)] = f2bf(x);
            }
        }
        __syncthreads();   // (2) H1 visible

        // ---- layer 2 + leaky + weighted pooling
        bf16x8 afr2[4];
#pragma unroll
        for (int ks = 0; ks < 4; ++ks) {
            int phys = (ks * 4 + kg) ^ (rA & 15);
            afr2[ks] = *reinterpret_cast<const bf16x8*>(&A[rA * 128 + phys * 8]);
        }
        float wr[4];
#pragma unroll
        for (int i = 0; i < 4; ++i) wr[i] = wrow[mt * 16 + kg * 4 + i];
        float part[4];
#pragma unroll
        for (int nt = 0; nt < 4; ++nt) {
            f32x4 acc = {0.f, 0.f, 0.f, 0.f};
            int n = nh * 64 + nt * 16 + nrow;
#pragma unroll
            for (int ks = 0; ks < 4; ++ks) {
                int phys = (ks * 4 + kg) ^ (n & 15);
                bf16x8 bfr = *reinterpret_cast<const bf16x8*>(&w2L[n * 128 + phys * 8]);
                acc = __builtin_amdgcn_mfma_f32_16x16x32_bf16(afr2[ks], bfr, acc, 0, 0, 0);
            }
            float s = 0.f;
#pragma unroll
            for (int i = 0; i < 4; ++i) {
                float x = acc[i] + b2r[nt];
                x = (x >= 0.f) ? x : 0.01f * x;
                s += x * wr[i];
            }
            part[nt] = s;
        }
#pragma unroll
        for (int nt = 0; nt < 4; ++nt) {
            float v = part[nt];
            v += __shfl_xor(v, 16);
            v += __shfl_xor(v, 32);
            part[nt] = v;
        }
        if (lane < 16) {
#pragma unroll
            for (int nt = 0; nt < 4; ++nt) pp[wv][nh * 64 + nt * 16 + lane] = part[nt];
        }
        __syncthreads();   // (3) pp complete

        if (t < 128) {
            int base = t >> 6;
            float s = pp[base][t] + pp[base + 2][t] + pp[base + 4][t] + pp[base + 6][t];
            int seg = locs_combos[2 * c];
            poolbf[(size_t)seg * 128 + t] = f2bf(s);
        }
        // ---- stage combo c+1 into aBuf[cur^1]
        if (j + 1 < CPB) {
            unsigned short* B = aBuf[cur ^ 1];
#pragma unroll
            for (int q = 0; q < 4; ++q) {
                int r = sl * 32 + pq * 4 + q;
                unsigned int lo = (unsigned int)f2bf((&pf[0].x)[q]) |
                                  ((unsigned int)f2bf((&pf[1].x)[q]) << 16);
                unsigned int hi = (unsigned int)f2bf((&pf[2].x)[q]) |
                                  ((unsigned int)f2bf((&pf[3].x)[q]) << 16);
                uint2 v2 = {lo, hi};
                *reinterpret_cast<uint2*>(
                    &B[r * 128 + (((d0 >> 3) ^ (r & 15)) << 3) + (d0 & 7)]) = v2;
            }
            cur ^= 1;
        }
        __syncthreads();   // (4) aBuf[next] ready; pp reads done
    }
}

// ---------------- K2: out = pooled @ Wout + bout  (transposed-operand MFMA) ---
// A = WoutT rows (g), B = pooled rows (b): D-fragment gives each lane 4
// CONSECUTIVE g columns -> dwordx4 stores, 16 per thread (was 64 dword),
// each instruction = 16 fully-covered 64B sectors (1 KB).
__global__ __launch_bounds__(256) void out_gemm(
    const unsigned short* __restrict__ poolbf, const unsigned short* __restrict__ woutT,
    const float* __restrict__ boutg, float* __restrict__ out)
{
    const int t = threadIdx.x;
    const int lane = t & 63, wv = t >> 6;
    const int nrow = lane & 15, kg = lane >> 4;
    const int id = blockIdx.x;                 // 5024 = 157 * 32
    const int by = id & 31, bx = id >> 5;      // 32 consecutive blocks share bx
    const int nb0 = bx * 128;                  // g base (cols of out)
    const int mb0 = by * 128 + wv * 32;        // b base for this wave (rows)

    // B-frags: pooled rows (b), k = d
    bf16x8 bfr[2][4];
#pragma unroll
    for (int bt = 0; bt < 2; ++bt) {
        int row = mb0 + bt * 16 + nrow;
#pragma unroll
        for (int ks = 0; ks < 4; ++ks)
            bfr[bt][ks] = *reinterpret_cast<const bf16x8*>(
                &poolbf[(size_t)row * 128 + ks * 32 + kg * 8]);
    }
#pragma unroll
    for (int gt = 0; gt < 8; ++gt) {
        int g = nb0 + gt * 16 + nrow;          // < 20096 always (padded)
        bf16x8 afr[4];
#pragma unroll
        for (int ks = 0; ks < 4; ++ks)
            afr[ks] = *reinterpret_cast<const bf16x8*>(
                &woutT[(size_t)g * 128 + ks * 32 + kg * 8]);
        f32x4 a0 = {0.f, 0.f, 0.f, 0.f}, a1 = {0.f, 0.f, 0.f, 0.f};
#pragma unroll
        for (int ks = 0; ks < 4; ++ks) {
            a0 = __builtin_amdgcn_mfma_f32_16x16x32_bf16(afr[ks], bfr[0][ks], a0, 0, 0, 0);
            a1 = __builtin_amdgcn_mfma_f32_16x16x32_bf16(afr[ks], bfr[1][ks], a1, 0, 0, 0);
        }
        int gs = nb0 + gt * 16 + kg * 4;       // 4 consecutive g per lane
        if (gs < GOUT) {                       // GOUT % 4 == 0 -> whole quad valid
            float4 b4 = *reinterpret_cast<const float4*>(&boutg[gs]);
            float4 o0, o1;
            o0.x = a0[0] + b4.x; o0.y = a0[1] + b4.y; o0.z = a0[2] + b4.z; o0.w = a0[3] + b4.w;
            o1.x = a1[0] + b4.x; o1.y = a1[1] + b4.y; o1.z = a1[2] + b4.z; o1.w = a1[3] + b4.w;
            int row0 = mb0 + nrow;
            int row1 = mb0 + 16 + nrow;
            *reinterpret_cast<float4*>(&out[(size_t)row0 * GOUT + gs]) = o0;
            *reinterpret_cast<float4*>(&out[(size_t)row1 * GOUT + gs]) = o1;
        }
    }
}

extern "C" void kernel_launch(void* const* d_in, const int* in_sizes, int n_in,
                              void* d_out, int out_size, void* d_ws, size_t ws_size,
                              hipStream_t stream) {
    const float* gene  = (const float*)d_in[0];
    const float* W1    = (const float*)d_in[1];
    const float* b1    = (const float*)d_in[2];
    const float* W2    = (const float*)d_in[3];
    const float* b2    = (const float*)d_in[4];
    const float* pw    = (const float*)d_in[5];
    const float* Wout  = (const float*)d_in[6];
    const float* bout  = (const float*)d_in[7];
    const int* locs_gene   = (const int*)d_in[8];
    const int* locs_combos = (const int*)d_in[9];
    float* out = (float*)d_out;

    char* ws = (char*)d_ws;
    unsigned short* w1t    = (unsigned short*)(ws);
    unsigned short* w2t    = (unsigned short*)(ws + 32768);
    unsigned short* woutT  = (unsigned short*)(ws + 65536);
    unsigned short* poolbf = (unsigned short*)(ws + 65536 + (size_t)GPAD * 256);

    hipLaunchKernelGGL(prep_weights, dim3(32), dim3(256), 0, stream, W1, W2, w1t, w2t);
    hipLaunchKernelGGL(prep_wout, dim3((GPAD + 255) / 256), dim3(256), 0, stream, Wout, woutT);
    hipLaunchKernelGGL(encoder_kernel, dim3(NB / CPB), dim3(512), 0, stream,
                       gene, b1, b2, pw, locs_gene, locs_combos, w1t, w2t, poolbf);
    hipLaunchKernelGGL(out_gemm, dim3(157 * 32), dim3(256), 0, stream,
                       poolbf, woutT, bout, out);
}

// Round 8
// 217.700 us; speedup vs baseline: 1.4229x; 1.1732x over previous
//
#include <hip/hip_runtime.h>
#include <hip/hip_bf16.h>

#define GENES 20000
#define DD    128
#define PP    32
#define HH    128
#define NB    4096
#define GOUT  20000
#define GPAD  20096   // GOUT padded to multiple of 128

typedef __attribute__((ext_vector_type(8))) short bf16x8;
typedef __attribute__((ext_vector_type(4))) float f32x4;

__device__ __forceinline__ unsigned short f2bf(float f) {
    unsigned int u = __float_as_uint(f);
    unsigned int lsb = (u >> 16) & 1u;
    u += 0x7fffu + lsb;                      // RTNE
    return (unsigned short)(u >> 16);
}
__device__ __forceinline__ float bf2f(unsigned short s) {
    return __uint_as_float(((unsigned int)s) << 16);
}

// XOR-swizzled ushort offset inside a [rows][128] bf16 tile (16B-chunk swizzle).
__device__ __forceinline__ int swz(int r, int c) {
    return r * 128 + (((c >> 3) ^ (r & 15)) << 3) + (c & 7);
}

// ---------------- K0a: W1,W2 -> swizzled bf16 transposed tiles ----------------
__global__ void prep_weights(const float* __restrict__ W1, const float* __restrict__ W2,
                             unsigned short* __restrict__ w1t, unsigned short* __restrict__ w2t) {
    int idx = blockIdx.x * 512 + threadIdx.x;
#pragma unroll
    for (int k = 0; k < 2; ++k, idx += 256) {
        int d = idx >> 7, h = idx & 127;
        int off = swz(h, d);       // W1T[h][d] = W1[d][h]
        w1t[off] = f2bf(W1[idx]);
        w2t[off] = f2bf(W2[idx]);
    }
}

// ---------------- K0b: Wout [128][20000] f32 -> WoutT [20096][128] bf16 -------
__global__ void prep_wout(const float* __restrict__ Wout, unsigned short* __restrict__ woutT) {
    int g = blockIdx.x * 256 + threadIdx.x;
    if (g >= GPAD) return;
    if (g < GOUT) {
        for (int d0 = 0; d0 < 128; d0 += 8) {
            unsigned short buf[8];
#pragma unroll
            for (int j = 0; j < 8; ++j) buf[j] = f2bf(Wout[(size_t)(d0 + j) * GOUT + g]);
            *reinterpret_cast<uint4*>(&woutT[(size_t)g * 128 + d0]) =
                *reinterpret_cast<const uint4*>(buf);
        }
    } else {
        uint4 z = {0u, 0u, 0u, 0u};
        for (int d0 = 0; d0 < 128; d0 += 8)
            *reinterpret_cast<uint4*>(&woutT[(size_t)g * 128 + d0]) = z;
    }
}

// ---------------- K1: persistent encoder, 2 combos/iter, 16 waves -------------
// R2 skeleton widened: 1024 threads, 4 waves/SIMD, 2 barriers per combo.
__global__ __launch_bounds__(1024, 4) void encoder_kernel(
    const float* __restrict__ gene, const float* __restrict__ b1g,
    const float* __restrict__ b2g, const float* __restrict__ pwg,
    const int* __restrict__ locs_gene, const int* __restrict__ locs_combos,
    const unsigned short* __restrict__ w1t, const unsigned short* __restrict__ w2t,
    unsigned short* __restrict__ poolbf)
{
    __shared__ __align__(16) unsigned short w1L[128 * 128];        // 32 KB swizzled
    __shared__ __align__(16) unsigned short w2L[128 * 128];        // 32 KB swizzled
    __shared__ __align__(16) unsigned short aBuf[2][2][64 * 128];  // 64 KB swizzled
    __shared__ float wrow[2][64];
    __shared__ float pp[2][8][128];

    const int t = threadIdx.x;
    const int lane = t & 63, wv = t >> 6;          // wv 0..15
    const int cb = wv >> 3;                        // combo half (== t>>9)
    const int w3 = wv & 7;
    const int nrow = lane & 15, kg = lane >> 4;
    const int mt = w3 >> 1, nh = w3 & 1;           // wave -> (M-tile, N-half)
    const int rA = mt * 16 + nrow;

    // ---- stage weights once per block
    {
        const uint4* s1 = reinterpret_cast<const uint4*>(w1t);
        const uint4* s2 = reinterpret_cast<const uint4*>(w2t);
        uint4* d1 = reinterpret_cast<uint4*>(w1L);
        uint4* d2 = reinterpret_cast<uint4*>(w2L);
        for (int i = t; i < 2048; i += 1024) { d1[i] = s1[i]; d2[i] = s2[i]; }
    }
    // ---- per-thread invariants
    float b1r[4], b2r[4];
#pragma unroll
    for (int nt = 0; nt < 4; ++nt) {
        int c = nh * 64 + nt * 16 + nrow;
        b1r[nt] = b1g[c]; b2r[nt] = b2g[c];
    }
    const float pwl = pwg[lane & 31];

    // staging decomposition (per 512-thread half): thread -> (slot, d-quad, p-quad)
    const int t9 = t & 511;
    const int sl = t9 >> 8;                // which gene of the combo
    const int w8 = t9 & 255;
    const int d0 = (w8 >> 3) * 4;          // 0,4,...,124
    const int pq = w8 & 7;                 // p-quad 0..7

    const int c0 = blockIdx.x * 16;        // 16 combos per block, 2 per iter

    float4 pf[4];
    auto loadCombo = [&](int j) {          // load this half's combo for iter j
        int c = c0 + 2 * j + cb;
        int gsel = locs_gene[2 * c + sl];
        const float* src = gene + (size_t)gsel * 4096;
#pragma unroll
        for (int i = 0; i < 4; ++i)
            pf[i] = *reinterpret_cast<const float4*>(&src[(d0 + i) * 32 + pq * 4]);
    };
    auto stageCombo = [&](int buf) {
#pragma unroll
        for (int q = 0; q < 4; ++q) {
            int r = sl * 32 + pq * 4 + q;
            unsigned int lo = (unsigned int)f2bf((&pf[0].x)[q]) |
                              ((unsigned int)f2bf((&pf[1].x)[q]) << 16);
            unsigned int hi = (unsigned int)f2bf((&pf[2].x)[q]) |
                              ((unsigned int)f2bf((&pf[3].x)[q]) << 16);
            uint2 v2 = {lo, hi};
            *reinterpret_cast<uint2*>(
                &aBuf[cb][buf][r * 128 + (((d0 >> 3) ^ (r & 15)) << 3) + (d0 & 7)]) = v2;
        }
    };

    // ---- prologue
    loadCombo(0);
    stageCombo(0);
    __syncthreads();

    int cur = 0;
    for (int j = 0; j < 8; ++j) {
        const int c = c0 + 2 * j + cb;
        if (j + 1 < 8) loadCombo(j + 1);   // prefetch next pair

        const unsigned short* A = aBuf[cb][cur];
        unsigned short* Aw = aBuf[cb][cur];

        // ---- wave w3==0 of each half: colsum -> mask -> softmax -> wrow[cb]
        if (w3 == 0) {
            float cs = 0.f;
#pragma unroll
            for (int cch = 0; cch < 16; ++cch) {
                int phys = cch ^ (lane & 15);
                bf16x8 v = *reinterpret_cast<const bf16x8*>(&A[lane * 128 + phys * 8]);
#pragma unroll
                for (int q = 0; q < 8; ++q) cs += bf2f((unsigned short)v[q]);
            }
            float other = __shfl_down(cs, 32);
            bool m = (cs != 0.f) || (other != 0.f);
            float logit = m ? pwl : -1e9f;
            float mx = logit;
#pragma unroll
            for (int o = 16; o >= 1; o >>= 1) mx = fmaxf(mx, __shfl_xor(mx, o, 32));
            float e = __expf(logit - mx);
            float se = e;
#pragma unroll
            for (int o = 16; o >= 1; o >>= 1) se += __shfl_xor(se, o, 32);
            float w = e / se;
            if (lane < 32) { wrow[cb][lane] = w; wrow[cb][lane + 32] = w; }
        }

        // ---- layer 1: H1 = leaky(A @ W1 + b1)
        bf16x8 afr[4];
#pragma unroll
        for (int ks = 0; ks < 4; ++ks) {
            int phys = (ks * 4 + kg) ^ (rA & 15);
            afr[ks] = *reinterpret_cast<const bf16x8*>(&A[rA * 128 + phys * 8]);
        }
        f32x4 acc1[4];
#pragma unroll
        for (int nt = 0; nt < 4; ++nt) {
            f32x4 acc = {0.f, 0.f, 0.f, 0.f};
            int n = nh * 64 + nt * 16 + nrow;
#pragma unroll
            for (int ks = 0; ks < 4; ++ks) {
                int phys = (ks * 4 + kg) ^ (n & 15);
                bf16x8 bfr = *reinterpret_cast<const bf16x8*>(&w1L[n * 128 + phys * 8]);
                acc = __builtin_amdgcn_mfma_f32_16x16x32_bf16(afr[ks], bfr, acc, 0, 0, 0);
            }
            acc1[nt] = acc;
        }
        __syncthreads();   // (1) aBuf reads + wrow writes done

        // ---- write H1 back into aBuf[cb][cur] (swizzled)
#pragma unroll
        for (int nt = 0; nt < 4; ++nt) {
            int cc = nh * 64 + nt * 16 + nrow;
#pragma unroll
            for (int i = 0; i < 4; ++i) {
                int r = mt * 16 + kg * 4 + i;
                float x = acc1[nt][i] + b1r[nt];
                x = (x >= 0.f) ? x : 0.01f * x;
                Aw[swz(r, cc)] = f2bf(x);
            }
        }
        __syncthreads();   // (2) H1 visible

        // ---- layer 2 + leaky + weighted pooling
        bf16x8 afr2[4];
#pragma unroll
        for (int ks = 0; ks < 4; ++ks) {
            int phys = (ks * 4 + kg) ^ (rA & 15);
            afr2[ks] = *reinterpret_cast<const bf16x8*>(&A[rA * 128 + phys * 8]);
        }
        float wr[4];
#pragma unroll
        for (int i = 0; i < 4; ++i) wr[i] = wrow[cb][mt * 16 + kg * 4 + i];
        float part[4];
#pragma unroll
        for (int nt = 0; nt < 4; ++nt) {
            f32x4 acc = {0.f, 0.f, 0.f, 0.f};
            int n = nh * 64 + nt * 16 + nrow;
#pragma unroll
            for (int ks = 0; ks < 4; ++ks) {
                int phys = (ks * 4 + kg) ^ (n & 15);
                bf16x8 bfr = *reinterpret_cast<const bf16x8*>(&w2L[n * 128 + phys * 8]);
                acc = __builtin_amdgcn_mfma_f32_16x16x32_bf16(afr2[ks], bfr, acc, 0, 0, 0);
            }
            float s = 0.f;
#pragma unroll
            for (int i = 0; i < 4; ++i) {
                float x = acc[i] + b2r[nt];
                x = (x >= 0.f) ? x : 0.01f * x;
                s += x * wr[i];
            }
            part[nt] = s;
        }
        // ---- stage next pair into the other buffer (overlaps pooling)
        if (j + 1 < 8) stageCombo(cur ^ 1);
        // ---- cross-lane then cross-wave reduction of pooled vector
#pragma unroll
        for (int nt = 0; nt < 4; ++nt) {
            float v = part[nt];
            v += __shfl_xor(v, 16);
            v += __shfl_xor(v, 32);
            part[nt] = v;
        }
        if (lane < 16) {
#pragma unroll
            for (int nt = 0; nt < 4; ++nt) pp[cb][w3][nh * 64 + nt * 16 + lane] = part[nt];
        }
        __syncthreads();   // (3) pp + staged buffer visible

        if (t9 < 128) {
            int base = t9 >> 6;
            float s = pp[cb][base][t9] + pp[cb][base + 2][t9]
                    + pp[cb][base + 4][t9] + pp[cb][base + 6][t9];
            int seg = locs_combos[2 * c];
            poolbf[(size_t)seg * 128 + t9] = f2bf(s);
        }
        if (j + 1 < 8) cur ^= 1;
        __syncthreads();   // (4) pp reads done; next buffer ready
    }
}

// ---------------- K2: out = pooled @ Wout + bout (R2 grid, dwordx4 stores) ----
__global__ __launch_bounds__(256) void out_gemm(
    const unsigned short* __restrict__ poolbf, const unsigned short* __restrict__ woutT,
    const float* __restrict__ boutg, float* __restrict__ out)
{
    const int t = threadIdx.x;
    const int lane = t & 63, wv = t >> 6;
    const int nrow = lane & 15, kg = lane >> 4;
    const int nb0 = blockIdx.x * 128;          // g base (cols), fastest-varying
    const int mb0 = blockIdx.y * 128 + wv * 32;

    // B-frags: pooled rows (b), k = d
    bf16x8 bfr[2][4];
#pragma unroll
    for (int bt = 0; bt < 2; ++bt) {
        int row = mb0 + bt * 16 + nrow;
#pragma unroll
        for (int ks = 0; ks < 4; ++ks)
            bfr[bt][ks] = *reinterpret_cast<const bf16x8*>(
                &poolbf[(size_t)row * 128 + ks * 32 + kg * 8]);
    }
#pragma unroll
    for (int gt = 0; gt < 8; ++gt) {
        int g = nb0 + gt * 16 + nrow;          // < 20096 always (padded)
        bf16x8 afr[4];
#pragma unroll
        for (int ks = 0; ks < 4; ++ks)
            afr[ks] = *reinterpret_cast<const bf16x8*>(
                &woutT[(size_t)g * 128 + ks * 32 + kg * 8]);
        f32x4 a0 = {0.f, 0.f, 0.f, 0.f}, a1 = {0.f, 0.f, 0.f, 0.f};
#pragma unroll
        for (int ks = 0; ks < 4; ++ks) {
            a0 = __builtin_amdgcn_mfma_f32_16x16x32_bf16(afr[ks], bfr[0][ks], a0, 0, 0, 0);
            a1 = __builtin_amdgcn_mfma_f32_16x16x32_bf16(afr[ks], bfr[1][ks], a1, 0, 0, 0);
        }
        int gs = nb0 + gt * 16 + kg * 4;       // 4 consecutive g per lane
        if (gs < GOUT) {                       // GOUT % 4 == 0 -> whole quad valid
            float4 b4 = *reinterpret_cast<const float4*>(&boutg[gs]);
            float4 o0, o1;
            o0.x = a0[0] + b4.x; o0.y = a0[1] + b4.y; o0.z = a0[2] + b4.z; o0.w = a0[3] + b4.w;
            o1.x = a1[0] + b4.x; o1.y = a1[1] + b4.y; o1.z = a1[2] + b4.z; o1.w = a1[3] + b4.w;
            int row0 = mb0 + nrow;
            int row1 = mb0 + 16 + nrow;
            *reinterpret_cast<float4*>(&out[(size_t)row0 * GOUT + gs]) = o0;
            *reinterpret_cast<float4*>(&out[(size_t)row1 * GOUT + gs]) = o1;
        }
    }
}

extern "C" void kernel_launch(void* const* d_in, const int* in_sizes, int n_in,
                              void* d_out, int out_size, void* d_ws, size_t ws_size,
                              hipStream_t stream) {
    const float* gene  = (const float*)d_in[0];
    const float* W1    = (const float*)d_in[1];
    const float* b1    = (const float*)d_in[2];
    const float* W2    = (const float*)d_in[3];
    const float* b2    = (const float*)d_in[4];
    const float* pw    = (const float*)d_in[5];
    const float* Wout  = (const float*)d_in[6];
    const float* bout  = (const float*)d_in[7];
    const int* locs_gene   = (const int*)d_in[8];
    const int* locs_combos = (const int*)d_in[9];
    float* out = (float*)d_out;

    char* ws = (char*)d_ws;
    unsigned short* w1t    = (unsigned short*)(ws);
    unsigned short* w2t    = (unsigned short*)(ws + 32768);
    unsigned short* woutT  = (unsigned short*)(ws + 65536);
    unsigned short* poolbf = (unsigned short*)(ws + 65536 + (size_t)GPAD * 256);

    hipLaunchKernelGGL(prep_weights, dim3(32), dim3(256), 0, stream, W1, W2, w1t, w2t);
    hipLaunchKernelGGL(prep_wout, dim3((GPAD + 255) / 256), dim3(256), 0, stream, Wout, woutT);
    hipLaunchKernelGGL(encoder_kernel, dim3(NB / 16), dim3(1024), 0, stream,
                       gene, b1, b2, pw, locs_gene, locs_combos, w1t, w2t, poolbf);
    hipLaunchKernelGGL(out_gemm, dim3(GPAD / 128, 32), dim3(256), 0, stream,
                       poolbf, woutT, bout, out);
}

// Round 9
// 211.695 us; speedup vs baseline: 1.4633x; 1.0284x over previous
//
#include <hip/hip_runtime.h>
#include <hip/hip_bf16.h>

#define GENES 20000
#define DD    128
#define PP    32
#define HH    128
#define NB    4096
#define GOUT  20000
#define GPAD  20096   // GOUT padded to multiple of 128
#define CPB   16      // combos per encoder block

typedef __attribute__((ext_vector_type(8))) short bf16x8;
typedef __attribute__((ext_vector_type(4))) float f32x4;

__device__ __forceinline__ unsigned short f2bf(float f) {
    unsigned int u = __float_as_uint(f);
    unsigned int lsb = (u >> 16) & 1u;
    u += 0x7fffu + lsb;                      // RTNE
    return (unsigned short)(u >> 16);
}
__device__ __forceinline__ float bf2f(unsigned short s) {
    return __uint_as_float(((unsigned int)s) << 16);
}

// XOR-swizzled ushort offset inside a [rows][128] bf16 tile (16B-chunk swizzle).
__device__ __forceinline__ int swz(int r, int c) {
    return r * 128 + (((c >> 3) ^ (r & 15)) << 3) + (c & 7);
}

// ---------------- K0a: W1,W2 -> swizzled bf16 transposed tiles ----------------
__global__ void prep_weights(const float* __restrict__ W1, const float* __restrict__ W2,
                             unsigned short* __restrict__ w1t, unsigned short* __restrict__ w2t) {
    int idx = blockIdx.x * 512 + threadIdx.x;
#pragma unroll
    for (int k = 0; k < 2; ++k, idx += 256) {
        int d = idx >> 7, h = idx & 127;
        int off = swz(h, d);       // W1T[h][d] = W1[d][h]
        w1t[off] = f2bf(W1[idx]);
        w2t[off] = f2bf(W2[idx]);
    }
}

// ---------------- K0b: Wout [128][20000] f32 -> WoutT [20096][128] bf16 -------
__global__ void prep_wout(const float* __restrict__ Wout, unsigned short* __restrict__ woutT) {
    int g = blockIdx.x * 256 + threadIdx.x;
    if (g >= GPAD) return;
    if (g < GOUT) {
        for (int d0 = 0; d0 < 128; d0 += 8) {
            unsigned short buf[8];
#pragma unroll
            for (int j = 0; j < 8; ++j) buf[j] = f2bf(Wout[(size_t)(d0 + j) * GOUT + g]);
            *reinterpret_cast<uint4*>(&woutT[(size_t)g * 128 + d0]) =
                *reinterpret_cast<const uint4*>(buf);
        }
    } else {
        uint4 z = {0u, 0u, 0u, 0u};
        for (int d0 = 0; d0 < 128; d0 += 8)
            *reinterpret_cast<uint4*>(&woutT[(size_t)g * 128 + d0]) = z;
    }
}

// ---------------- K1: persistent encoder, pipelined gather (R2 exact) ---------
__global__ __launch_bounds__(512) void encoder_kernel(
    const float* __restrict__ gene, const float* __restrict__ b1g,
    const float* __restrict__ b2g, const float* __restrict__ pwg,
    const int* __restrict__ locs_gene, const int* __restrict__ locs_combos,
    const unsigned short* __restrict__ w1t, const unsigned short* __restrict__ w2t,
    unsigned short* __restrict__ poolbf)
{
    __shared__ __align__(16) unsigned short w1L[128 * 128];     // 32 KB swizzled
    __shared__ __align__(16) unsigned short w2L[128 * 128];     // 32 KB swizzled
    __shared__ __align__(16) unsigned short aBuf[2][64 * 128];  // 2 x 16 KB swizzled
    __shared__ float wrow[64];
    __shared__ float pp[8][128];

    const int t = threadIdx.x;
    const int lane = t & 63, wv = t >> 6;
    const int nrow = lane & 15, kg = lane >> 4;
    const int mt = wv >> 1, nh = wv & 1;          // wave -> (M-tile, N-half)
    const int rA = mt * 16 + nrow;

    // ---- stage weights once per block
    {
        const uint4* s1 = reinterpret_cast<const uint4*>(w1t);
        const uint4* s2 = reinterpret_cast<const uint4*>(w2t);
        uint4* d1 = reinterpret_cast<uint4*>(w1L);
        uint4* d2 = reinterpret_cast<uint4*>(w2L);
        for (int i = t; i < 2048; i += 512) { d1[i] = s1[i]; d2[i] = s2[i]; }
    }
    // ---- per-thread invariants
    float b1r[4], b2r[4];
#pragma unroll
    for (int nt = 0; nt < 4; ++nt) {
        int c = nh * 64 + nt * 16 + nrow;
        b1r[nt] = b1g[c]; b2r[nt] = b2g[c];
    }
    const float pwl = pwg[lane & 31];

    // staging decomposition: thread -> (gene slot, d-quad, p-quad)
    const int sl = t >> 8;                 // 0..1 (which gene of the combo)
    const int w8 = t & 255;
    const int d0 = (w8 >> 3) * 4;          // 0,4,...,124
    const int pq = w8 & 7;                 // p-quad 0..7

    const int c0 = blockIdx.x * CPB;

    float4 pf[4];
    // ---- prologue: load + stage combo c0 into aBuf[0]
    {
        int g0 = locs_gene[2 * c0], g1 = locs_gene[2 * c0 + 1];
        const float* src = gene + (size_t)(sl ? g1 : g0) * 4096;
#pragma unroll
        for (int i = 0; i < 4; ++i)
            pf[i] = *reinterpret_cast<const float4*>(&src[(d0 + i) * 32 + pq * 4]);
#pragma unroll
        for (int q = 0; q < 4; ++q) {
            int r = sl * 32 + pq * 4 + q;
            unsigned int lo = (unsigned int)f2bf((&pf[0].x)[q]) |
                              ((unsigned int)f2bf((&pf[1].x)[q]) << 16);
            unsigned int hi = (unsigned int)f2bf((&pf[2].x)[q]) |
                              ((unsigned int)f2bf((&pf[3].x)[q]) << 16);
            uint2 v2 = {lo, hi};
            *reinterpret_cast<uint2*>(
                &aBuf[0][r * 128 + (((d0 >> 3) ^ (r & 15)) << 3) + (d0 & 7)]) = v2;
        }
    }
    __syncthreads();

    int cur = 0;
    for (int j = 0; j < CPB; ++j) {
        const int c = c0 + j;
        // ---- issue prefetch loads for combo c+1 (latency hides under MFMA)
        if (j + 1 < CPB) {
            int g0 = locs_gene[2 * (c + 1)], g1 = locs_gene[2 * (c + 1) + 1];
            const float* src = gene + (size_t)(sl ? g1 : g0) * 4096;
#pragma unroll
            for (int i = 0; i < 4; ++i)
                pf[i] = *reinterpret_cast<const float4*>(&src[(d0 + i) * 32 + pq * 4]);
        }
        const unsigned short* A = aBuf[cur];
        unsigned short* Aw = aBuf[cur];

        // ---- wave 0: per-row colsum -> mask -> softmax -> wrow[64]
        if (wv == 0) {
            float cs = 0.f;
#pragma unroll
            for (int cch = 0; cch < 16; ++cch) {
                int phys = cch ^ (lane & 15);
                bf16x8 v = *reinterpret_cast<const bf16x8*>(&A[lane * 128 + phys * 8]);
#pragma unroll
                for (int q = 0; q < 8; ++q) cs += bf2f((unsigned short)v[q]);
            }
            float other = __shfl_down(cs, 32);
            bool m = (cs != 0.f) || (other != 0.f);
            float logit = m ? pwl : -1e9f;
            float mx = logit;
#pragma unroll
            for (int o = 16; o >= 1; o >>= 1) mx = fmaxf(mx, __shfl_xor(mx, o, 32));
            float e = __expf(logit - mx);
            float se = e;
#pragma unroll
            for (int o = 16; o >= 1; o >>= 1) se += __shfl_xor(se, o, 32);
            float w = e / se;
            if (lane < 32) { wrow[lane] = w; wrow[lane + 32] = w; }
        }

        // ---- layer 1: H1 = leaky(A @ W1 + b1)
        bf16x8 afr[4];
#pragma unroll
        for (int ks = 0; ks < 4; ++ks) {
            int phys = (ks * 4 + kg) ^ (rA & 15);
            afr[ks] = *reinterpret_cast<const bf16x8*>(&A[rA * 128 + phys * 8]);
        }
        f32x4 acc1[4];
#pragma unroll
        for (int nt = 0; nt < 4; ++nt) {
            f32x4 acc = {0.f, 0.f, 0.f, 0.f};
            int n = nh * 64 + nt * 16 + nrow;
#pragma unroll
            for (int ks = 0; ks < 4; ++ks) {
                int phys = (ks * 4 + kg) ^ (n & 15);
                bf16x8 bfr = *reinterpret_cast<const bf16x8*>(&w1L[n * 128 + phys * 8]);
                acc = __builtin_amdgcn_mfma_f32_16x16x32_bf16(afr[ks], bfr, acc, 0, 0, 0);
            }
            acc1[nt] = acc;
        }
        __syncthreads();   // (1) all aBuf[cur] reads + wrow write done

        // ---- write H1 back into aBuf[cur] (swizzled)
#pragma unroll
        for (int nt = 0; nt < 4; ++nt) {
            int cc = nh * 64 + nt * 16 + nrow;
#pragma unroll
            for (int i = 0; i < 4; ++i) {
                int r = mt * 16 + kg * 4 + i;
                float x = acc1[nt][i] + b1r[nt];
                x = (x >= 0.f) ? x : 0.01f * x;
                Aw[swz(r, cc)] = f2bf(x);
            }
        }
        __syncthreads();   // (2) H1 visible

        // ---- layer 2 + leaky + weighted pooling
        bf16x8 afr2[4];
#pragma unroll
        for (int ks = 0; ks < 4; ++ks) {
            int phys = (ks * 4 + kg) ^ (rA & 15);
            afr2[ks] = *reinterpret_cast<const bf16x8*>(&A[rA * 128 + phys * 8]);
        }
        float wr[4];
#pragma unroll
        for (int i = 0; i < 4; ++i) wr[i] = wrow[mt * 16 + kg * 4 + i];
        float part[4];
#pragma unroll
        for (int nt = 0; nt < 4; ++nt) {
            f32x4 acc = {0.f, 0.f, 0.f, 0.f};
            int n = nh * 64 + nt * 16 + nrow;
#pragma unroll
            for (int ks = 0; ks < 4; ++ks) {
                int phys = (ks * 4 + kg) ^ (n & 15);
                bf16x8 bfr = *reinterpret_cast<const bf16x8*>(&w2L[n * 128 + phys * 8]);
                acc = __builtin_amdgcn_mfma_f32_16x16x32_bf16(afr2[ks], bfr, acc, 0, 0, 0);
            }
            float s = 0.f;
#pragma unroll
            for (int i = 0; i < 4; ++i) {
                float x = acc[i] + b2r[nt];
                x = (x >= 0.f) ? x : 0.01f * x;
                s += x * wr[i];
            }
            part[nt] = s;
        }
#pragma unroll
        for (int nt = 0; nt < 4; ++nt) {
            float v = part[nt];
            v += __shfl_xor(v, 16);
            v += __shfl_xor(v, 32);
            part[nt] = v;
        }
        if (lane < 16) {
#pragma unroll
            for (int nt = 0; nt < 4; ++nt) pp[wv][nh * 64 + nt * 16 + lane] = part[nt];
        }
        __syncthreads();   // (3) pp complete

        if (t < 128) {
            int base = t >> 6;
            float s = pp[base][t] + pp[base + 2][t] + pp[base + 4][t] + pp[base + 6][t];
            int seg = locs_combos[2 * c];
            poolbf[(size_t)seg * 128 + t] = f2bf(s);
        }
        // ---- stage combo c+1 into aBuf[cur^1]
        if (j + 1 < CPB) {
            unsigned short* B = aBuf[cur ^ 1];
#pragma unroll
            for (int q = 0; q < 4; ++q) {
                int r = sl * 32 + pq * 4 + q;
                unsigned int lo = (unsigned int)f2bf((&pf[0].x)[q]) |
                                  ((unsigned int)f2bf((&pf[1].x)[q]) << 16);
                unsigned int hi = (unsigned int)f2bf((&pf[2].x)[q]) |
                                  ((unsigned int)f2bf((&pf[3].x)[q]) << 16);
                uint2 v2 = {lo, hi};
                *reinterpret_cast<uint2*>(
                    &B[r * 128 + (((d0 >> 3) ^ (r & 15)) << 3) + (d0 & 7)]) = v2;
            }
            cur ^= 1;
        }
        __syncthreads();   // (4) aBuf[next] ready; pp reads done
    }
}

// ---------------- K2: out_gemm with LDS-transposed coalesced epilogue ---------
// Two g-half passes: MFMA -> LDS [128 b][64 g] f32 -> stores where each
// 16-lane group writes a 256 B CONTIGUOUS span of one out row (was 16
// scattered 64 B sectors per instruction).
__global__ __launch_bounds__(256, 4) void out_gemm(
    const unsigned short* __restrict__ poolbf, const unsigned short* __restrict__ woutT,
    const float* __restrict__ boutg, float* __restrict__ out)
{
    __shared__ float tile[128][68];            // 34.8 KB, 16B-aligned rows, 2-way banks
    const int t = threadIdx.x;
    const int lane = t & 63, wv = t >> 6;
    const int nrow = lane & 15, kg = lane >> 4;
    const int nb0 = blockIdx.x * 128;          // g base (fastest-varying blocks)
    const int brow0 = blockIdx.y * 128;        // global b base
    const int mb0 = wv * 32;                   // b offset inside tile

    // B-frags: pooled rows (b), k = d
    bf16x8 bfr[2][4];
#pragma unroll
    for (int bt = 0; bt < 2; ++bt) {
        int row = brow0 + mb0 + bt * 16 + nrow;
#pragma unroll
        for (int ks = 0; ks < 4; ++ks)
            bfr[bt][ks] = *reinterpret_cast<const bf16x8*>(
                &poolbf[(size_t)row * 128 + ks * 32 + kg * 8]);
    }

#pragma unroll
    for (int p = 0; p < 2; ++p) {
        // ---- compute 4 g-tiles (64 g) of the output tile
        f32x4 acc[4][2];
#pragma unroll
        for (int q = 0; q < 4; ++q) {
            int g = nb0 + (p * 4 + q) * 16 + nrow;     // < GPAD (padded rows are zero)
            bf16x8 afr[4];
#pragma unroll
            for (int ks = 0; ks < 4; ++ks)
                afr[ks] = *reinterpret_cast<const bf16x8*>(
                    &woutT[(size_t)g * 128 + ks * 32 + kg * 8]);
            f32x4 a0 = {0.f, 0.f, 0.f, 0.f}, a1 = {0.f, 0.f, 0.f, 0.f};
#pragma unroll
            for (int ks = 0; ks < 4; ++ks) {
                a0 = __builtin_amdgcn_mfma_f32_16x16x32_bf16(afr[ks], bfr[0][ks], a0, 0, 0, 0);
                a1 = __builtin_amdgcn_mfma_f32_16x16x32_bf16(afr[ks], bfr[1][ks], a1, 0, 0, 0);
            }
            acc[q][0] = a0; acc[q][1] = a1;
        }
        __syncthreads();   // prior pass's LDS reads complete
        // ---- deposit bias-added f32 into LDS (2-way banks, free)
#pragma unroll
        for (int q = 0; q < 4; ++q) {
            int gcol = nb0 + (p * 4 + q) * 16 + kg * 4;
            float4 b4 = {0.f, 0.f, 0.f, 0.f};
            if (gcol < GOUT) b4 = *reinterpret_cast<const float4*>(&boutg[gcol]);
            int gl = q * 16 + kg * 4;                  // local col in half
#pragma unroll
            for (int bt = 0; bt < 2; ++bt) {
                int row = mb0 + bt * 16 + nrow;
                float4 o;
                o.x = acc[q][bt][0] + b4.x; o.y = acc[q][bt][1] + b4.y;
                o.z = acc[q][bt][2] + b4.z; o.w = acc[q][bt][3] + b4.w;
                *reinterpret_cast<float4*>(&tile[row][gl]) = o;
            }
        }
        __syncthreads();   // tile ready
        // ---- coalesced stores: 16 lanes = 256 B contiguous of one row
        int cl = (t & 15) * 4;                         // local col 0..60
        int gcol = nb0 + p * 64 + cl;
        if (gcol < GOUT) {
#pragma unroll
            for (int rnd = 0; rnd < 8; ++rnd) {
                int rl = rnd * 16 + (t >> 4);          // local row 0..127
                float4 v = *reinterpret_cast<const float4*>(&tile[rl][cl]);
                *reinterpret_cast<float4*>(&out[(size_t)(brow0 + rl) * GOUT + gcol]) = v;
            }
        }
    }
}

extern "C" void kernel_launch(void* const* d_in, const int* in_sizes, int n_in,
                              void* d_out, int out_size, void* d_ws, size_t ws_size,
                              hipStream_t stream) {
    const float* gene  = (const float*)d_in[0];
    const float* W1    = (const float*)d_in[1];
    const float* b1    = (const float*)d_in[2];
    const float* W2    = (const float*)d_in[3];
    const float* b2    = (const float*)d_in[4];
    const float* pw    = (const float*)d_in[5];
    const float* Wout  = (const float*)d_in[6];
    const float* bout  = (const float*)d_in[7];
    const int* locs_gene   = (const int*)d_in[8];
    const int* locs_combos = (const int*)d_in[9];
    float* out = (float*)d_out;

    char* ws = (char*)d_ws;
    unsigned short* w1t    = (unsigned short*)(ws);
    unsigned short* w2t    = (unsigned short*)(ws + 32768);
    unsigned short* woutT  = (unsigned short*)(ws + 65536);
    unsigned short* poolbf = (unsigned short*)(ws + 65536 + (size_t)GPAD * 256);

    hipLaunchKernelGGL(prep_weights, dim3(32), dim3(256), 0, stream, W1, W2, w1t, w2t);
    hipLaunchKernelGGL(prep_wout, dim3((GPAD + 255) / 256), dim3(256), 0, stream, Wout, woutT);
    hipLaunchKernelGGL(encoder_kernel, dim3(NB / CPB), dim3(512), 0, stream,
                       gene, b1, b2, pw, locs_gene, locs_combos, w1t, w2t, poolbf);
    hipLaunchKernelGGL(out_gemm, dim3(GPAD / 128, 32), dim3(256), 0, stream,
                       poolbf, woutT, bout, out);
}